// Round 21
// baseline (79.996 us; speedup 1.0000x reference)
//
#include <hip/hip_runtime.h>
#include <hip/hip_fp16.h>

// Adaptive downsampler: B=8, C=3, 1024x1024 -> 512x512, K2=9 taps,
// bilinear gather from reflect-padded (pad=1) image, weighted by kernels.
// R21 = R17/R20 base (fp16 packed-pair planar LDS 25x136/40960B, 512-thr
//       64x8 patch, 27-wide nt preload, XCD slab swizzle, plain stores)
//       + SINGLE-BASIC-BLOCK tap loop: cheap setup (trunc-as-floor,
//       unsigned window test), med3-clamped LDS index, cndmask-zeroed
//       weights, unconditional ds_read2+fdot2 -> scheduler can hoist
//       reads across taps (R15 retried without its 3 confounds: padded
//       clips, no-fdot2, 52KB LDS). Cold __any(miss) block adds exact
//       fp32 contribution (zero-weight taps contributed exactly 0).
constexpr int B_  = 8;
constexpr int C_  = 3;
constexpr int H_  = 1024;
constexpr int W_  = 1024;
constexpr int HO_ = 512;
constexpr int WO_ = 512;
constexpr int K2_ = 9;
constexpr int KS_ = 3;
constexpr int HP_ = H_ + 2;   // padded height (pad=1)
constexpr int WP_ = W_ + 2;   // padded width
constexpr int TPB_  = 512;
constexpr int NBLK_ = (B_ * HO_ * WO_) / TPB_;  // 4096 blocks
constexpr int NXCD_ = 8;

// LDS window: WY_ rows x WX_ pair-cols x 3 channels (half2 per entry)
constexpr int WY_  = 25;
constexpr int WX_  = 136;
constexpr int WX4_ = WX_ / 4;              // 34 staging units per row
constexpr int WCH_ = WY_ * WX_;            // 3400 entries per channel
constexpr int NF4_ = 3 * WY_ * WX4_;       // 2550 staging units

typedef __fp16 h2v __attribute__((ext_vector_type(2)));

__device__ __forceinline__ float2 ld2(const float* p) {
    float2 r;
    __builtin_memcpy(&r, p, sizeof(float2));   // global_load_dwordx2
    return r;
}

__device__ __forceinline__ h2v ldh2(const __half2* p) {
    h2v r;
    __builtin_memcpy(&r, p, sizeof(h2v));      // ds_read_b32 (read2-paired)
    return r;
}

__global__ __launch_bounds__(TPB_) void ds_kernel(
    const float* __restrict__ img,
    const float* __restrict__ kern,
    const float* __restrict__ offh,
    const float* __restrict__ offv,
    const float* __restrict__ unit_p,
    float* __restrict__ out)
{
    const int HWo = HO_ * WO_;                       // 262144
    __shared__ __half2 shp[3 * WCH_];                // 40800 B -> 40960 alloc

    // XCD swizzle: block i runs on XCD i%8; contiguous 512-block slab
    // per XCD = one batch, oy-ordered -> image window L2-resident.
    const int wg  = blockIdx.x;
    const int nid = (wg & (NXCD_ - 1)) * (NBLK_ / NXCD_) + (wg >> 3);

    // 2D patch decode: nid = b*512 + oyt*8 + oxt
    const int b   = nid >> 9;
    const int q   = nid & 511;
    const int oyt = q >> 3;             // 0..63: 8-row oy group
    const int oxt = q & 7;              // 0..7:  64-px ox chunk
    const int wv  = threadIdx.x >> 6;   // 0..7
    const int ln  = threadIdx.x & 63;
    const int oy  = oyt * 8 + wv;
    const int ox  = oxt * 64 + ln;

    const float unit = unit_p[0];
    const float* imgb = img + (size_t)b * (C_ * H_ * W_);
    const int kbase = b * (K2_ * HWo) + oy * WO_ + ox;   // < 2^25

    // Window origin (orig-image coords), x 4-aligned for float4 staging.
    int wxlo = 128 * oxt - 4;
    wxlo = wxlo < 0 ? 0 : (wxlo > W_ - WX_ ? W_ - WX_ : wxlo);   // 0..888, %4==0
    int wylo = 16 * oyt - 4;
    wylo = wylo < 0 ? 0 : (wylo > H_ - WY_ ? H_ - WY_ : wylo);   // 0..999

    // Phase 1: all 27 stream loads in flight (read-once -> nontemporal).
    float wk[K2_], oh[K2_], ov[K2_];
#pragma unroll
    for (int k = 0; k < K2_; ++k) {
        wk[k] = __builtin_nontemporal_load(kern + kbase + k * HWo);
        oh[k] = __builtin_nontemporal_load(offh + kbase + k * HWo);
        ov[k] = __builtin_nontemporal_load(offv + kbase + k * HWo);
    }

    // Phase 2: stage window into LDS as packed pairs:
    // shp[ch][row][c] = half2(img[row][c], img[row][c+1]).
#pragma unroll
    for (int i = 0; i < 5; ++i) {
        const int it = threadIdx.x + i * TPB_;
        if (it < NF4_) {
            const int ch  = it / (WY_ * WX4_);
            const int rem = it - ch * (WY_ * WX4_);
            const int row = rem / WX4_;
            const int c4  = rem - row * WX4_;
            const float* src = imgb + ch * (H_ * W_) + (wylo + row) * W_ + wxlo;
            const float4 v = ((const float4*)src)[c4];
            int gx = 4 * c4 + 4;                       // next element
            gx = (wxlo + gx > W_ - 1) ? (W_ - 1 - wxlo) : gx;  // clamp (unread pair)
            const float nx = src[gx];
            __half2 p0 = __float22half2_rn(make_float2(v.x, v.y));
            __half2 p1 = __float22half2_rn(make_float2(v.y, v.z));
            __half2 p2 = __float22half2_rn(make_float2(v.z, v.w));
            __half2 p3 = __float22half2_rn(make_float2(v.w, nx));
            __half2* dst = shp + ch * WCH_ + row * WX_ + 4 * c4;
            dst[0] = p0; dst[1] = p1; dst[2] = p2; dst[3] = p3;
        }
    }
    __syncthreads();

    // (ox+0.5)/WO*W - 0.5 == 2*ox + 0.5  (exact in fp32; W/WO = 2)
    const float cx = 2.0f * (float)ox + 0.5f;
    const float cy = 2.0f * (float)oy + 0.5f;

    float acc0 = 0.0f, acc1 = 0.0f, acc2 = 0.0f;
    unsigned miss = 0u;

    // Phase 3: single-basic-block tap loop (no control flow): miss-lanes
    // get zero weights + clamped (valid) LDS index -> exact no-op.
#pragma unroll
    for (int k = 0; k < K2_; ++k) {
        const float px = cx + (float)(k % KS_) + oh[k] * unit;
        const float py = cy + (float)(k / KS_) + ov[k] * unit;

        // trunc == floor whenever the tap lands in-window (px,py >= 1);
        // otherwise the unsigned test fails -> miss -> exact cold path.
        const int xi = (int)px;
        const int yi = (int)py;
        const float a  = px - (float)xi;
        const float bt = py - (float)yi;

        const int xr = xi - (wxlo + 1);
        const int yr = yi - (wylo + 1);
        const bool inwin = ((unsigned)xr <= (unsigned)(WX_ - 2)) &
                           ((unsigned)yr <= (unsigned)(WY_ - 2));
        miss |= (inwin ? 0u : 1u) << k;

        const float wt = inwin ? wk[k] * (1.0f - bt) : 0.0f;
        const float wb = inwin ? wk[k] * bt          : 0.0f;
        const float ax0 = 1.0f - a;
        const h2v at = __builtin_amdgcn_cvt_pkrtz(wt * ax0, wt * a);
        const h2v ab = __builtin_amdgcn_cvt_pkrtz(wb * ax0, wb * a);

        // clamp index into window (v_med3_i32); data read is valid, and
        // zero weights nullify it exactly on miss.
        const int xrc = xr < 0 ? 0 : (xr > WX_ - 2 ? WX_ - 2 : xr);
        const int yrc = yr < 0 ? 0 : (yr > WY_ - 2 ? WY_ - 2 : yr);
        const int i_t = yrc * WX_ + xrc;

        {
            const __half2* hp = shp;
            acc0 = __builtin_amdgcn_fdot2(ldh2(hp + i_t),       at, acc0, false);
            acc0 = __builtin_amdgcn_fdot2(ldh2(hp + i_t + WX_), ab, acc0, false);
        }
        {
            const __half2* hp = shp + WCH_;
            acc1 = __builtin_amdgcn_fdot2(ldh2(hp + i_t),       at, acc1, false);
            acc1 = __builtin_amdgcn_fdot2(ldh2(hp + i_t + WX_), ab, acc1, false);
        }
        {
            const __half2* hp = shp + 2 * WCH_;
            acc2 = __builtin_amdgcn_fdot2(ldh2(hp + i_t),       at, acc2, false);
            acc2 = __builtin_amdgcn_fdot2(ldh2(hp + i_t + WX_), ab, acc2, false);
        }
    }

    // Cold exact fallback: add the exact fp32 contribution of missed taps
    // (reloads stream values from global to keep hot live-ranges short).
    if (__any(miss != 0u)) {
#pragma unroll
        for (int k = 0; k < K2_; ++k) {
            if (miss & (1u << k)) {
                const float wkf = kern[kbase + k * HWo];
                const float ohf = offh[kbase + k * HWo];
                const float ovf = offv[kbase + k * HWo];
                const float px = cx + (float)(k % KS_) + ohf * unit;
                const float py = cy + (float)(k / KS_) + ovf * unit;
                const float fx = floorf(px);
                const float fy = floorf(py);
                const float af = px - fx;
                const float bf = py - fy;

                int xL = (int)fx; xL = xL < 0 ? 0 : (xL > WP_ - 1 ? WP_ - 1 : xL);
                int xR = xL + 1;  xR = xR > WP_ - 1 ? WP_ - 1 : xR;
                int yT = (int)fy; yT = yT < 0 ? 0 : (yT > HP_ - 1 ? HP_ - 1 : yT);
                int yB = yT + 1;  yB = yB > HP_ - 1 ? HP_ - 1 : yB;

                int xl = xL - 1; xl = (xl < 0) ? -xl : (xl >= W_ ? 2 * W_ - 2 - xl : xl);
                int xr2 = xR - 1; xr2 = (xr2 < 0) ? -xr2 : (xr2 >= W_ ? 2 * W_ - 2 - xr2 : xr2);
                int yt = yT - 1; yt = (yt < 0) ? -yt : (yt >= H_ ? 2 * H_ - 2 - yt : yt);
                int yb = yB - 1; yb = (yb < 0) ? -yb : (yb >= H_ ? 2 * H_ - 2 - yb : yb);

                const int base = xl < xr2 ? xl : xr2;
                const float ax0 = ((xl == base) ? (1.0f - af) : 0.0f)
                                + ((xr2 == base) ? af : 0.0f);
                const float ax1 = 1.0f - ax0;
                const float wt = wkf * (1.0f - bf);
                const float wb = wkf * bf;

                const int r0 = yt * W_ + base;
                const int r1 = yb * W_ + base;
                {
                    const float2 v = ld2(imgb + r0);
                    const float2 u = ld2(imgb + r1);
                    acc0 = fmaf(wt, fmaf(ax0, v.x, ax1 * v.y),
                           fmaf(wb, fmaf(ax0, u.x, ax1 * u.y), acc0));
                }
                {
                    const float2 v = ld2(imgb + H_ * W_ + r0);
                    const float2 u = ld2(imgb + H_ * W_ + r1);
                    acc1 = fmaf(wt, fmaf(ax0, v.x, ax1 * v.y),
                           fmaf(wb, fmaf(ax0, u.x, ax1 * u.y), acc1));
                }
                {
                    const float2 v = ld2(imgb + 2 * H_ * W_ + r0);
                    const float2 u = ld2(imgb + 2 * H_ * W_ + r1);
                    acc2 = fmaf(wt, fmaf(ax0, v.x, ax1 * v.y),
                           fmaf(wb, fmaf(ax0, u.x, ax1 * u.y), acc2));
                }
            }
        }
    }

    const int obase = b * (C_ * HWo) + oy * WO_ + ox;
    out[obase]           = acc0;
    out[obase + HWo]     = acc1;
    out[obase + 2 * HWo] = acc2;
}

extern "C" void kernel_launch(void* const* d_in, const int* in_sizes, int n_in,
                              void* d_out, int out_size, void* d_ws, size_t ws_size,
                              hipStream_t stream) {
    const float* img  = (const float*)d_in[0];
    const float* kern = (const float*)d_in[1];
    const float* offh = (const float*)d_in[2];
    const float* offv = (const float*)d_in[3];
    const float* unit = (const float*)d_in[4];
    float* out = (float*)d_out;

    ds_kernel<<<NBLK_, TPB_, 0, stream>>>(img, kern, offh, offv, unit, out);
}

// Round 22
// 67.380 us; speedup vs baseline: 1.1872x; 1.1872x over previous
//
#include <hip/hip_runtime.h>
#include <hip/hip_fp16.h>

// Adaptive downsampler: B=8, C=3, 1024x1024 -> 512x512, K2=9 taps,
// bilinear gather from reflect-padded (pad=1) image, weighted by kernels.
// FINAL = R17 (66.0us, session best). Structure and why each piece exists:
//  - 512-thr blocks, 64x8 output patch per block (wave w -> oy row w,
//    lanes -> 64 consecutive ox): gather locality in L1 across the block's
//    waves (R6->R7 win). 1024-thr blocks regress (barrier straggler tail).
//  - XCD slab swizzle: each XCD owns one batch, oy-ordered -> image window
//    stays in its 4MB L2 (FETCH 511->304->160 MB across R3->R5).
//  - 27-wide nontemporal stream preload (kern/offh/offv): all in flight
//    before staging; nt keeps single-use streams from evicting the image.
//  - LDS window 25x136 pair-cols x 3ch as packed half2 (img[c], img[c+1]):
//    bilinear x-pair = 1 dword -> 27 ds_read2/thread; 40960B alloc.
//  - fdot2 bilinear: fold row weights into packed half2 (cvt_pkrtz), each
//    channel-row = 1 v_dot2_f32_f16 (R17 win: VALU 42->37%, dur 72->66).
//  - branchy fast path + exact fp32 clip/reflect fallback: branchless
//    variants (R15/R21) and pre-barrier setup (R18) all collapse occupancy.
//  - plain stores (nt stores at one point masked a spill issue; plain is
//    write-combined and correct).
// Nulled levers (do not retry): bank-conflict layouts (R12/R14), b64
// channel-interleave (R19), launch_bounds min-waves (R7/R13), 4-blocks/CU
// LDS cap (R16), further VALU micro-cuts (R20).
constexpr int B_  = 8;
constexpr int C_  = 3;
constexpr int H_  = 1024;
constexpr int W_  = 1024;
constexpr int HO_ = 512;
constexpr int WO_ = 512;
constexpr int K2_ = 9;
constexpr int KS_ = 3;
constexpr int HP_ = H_ + 2;   // padded height (pad=1)
constexpr int WP_ = W_ + 2;   // padded width
constexpr int TPB_  = 512;
constexpr int NBLK_ = (B_ * HO_ * WO_) / TPB_;  // 4096 blocks
constexpr int NXCD_ = 8;

// LDS window: WY_ rows x WX_ pair-cols x 3 channels (half2 per entry)
constexpr int WY_  = 25;
constexpr int WX_  = 136;
constexpr int WX4_ = WX_ / 4;              // 34 staging units per row
constexpr int WCH_ = WY_ * WX_;            // 3400 entries per channel
constexpr int NF4_ = 3 * WY_ * WX4_;       // 2550 staging units

typedef __fp16 h2v __attribute__((ext_vector_type(2)));

__device__ __forceinline__ float2 ld2(const float* p) {
    float2 r;
    __builtin_memcpy(&r, p, sizeof(float2));   // global_load_dwordx2
    return r;
}

__device__ __forceinline__ h2v ldh2(const __half2* p) {
    h2v r;
    __builtin_memcpy(&r, p, sizeof(h2v));      // ds_read_b32 (read2-paired)
    return r;
}

__global__ __launch_bounds__(TPB_) void ds_kernel(
    const float* __restrict__ img,
    const float* __restrict__ kern,
    const float* __restrict__ offh,
    const float* __restrict__ offv,
    const float* __restrict__ unit_p,
    float* __restrict__ out)
{
    const int HWo = HO_ * WO_;                       // 262144
    __shared__ __half2 shp[3 * WCH_];                // 40800 B -> 40960 alloc

    // XCD swizzle: block i runs on XCD i%8; contiguous 512-block slab
    // per XCD = one batch, oy-ordered -> image window L2-resident.
    const int wg  = blockIdx.x;
    const int nid = (wg & (NXCD_ - 1)) * (NBLK_ / NXCD_) + (wg >> 3);

    // 2D patch decode: nid = b*512 + oyt*8 + oxt
    const int b   = nid >> 9;
    const int q   = nid & 511;
    const int oyt = q >> 3;             // 0..63: 8-row oy group
    const int oxt = q & 7;              // 0..7:  64-px ox chunk
    const int wv  = threadIdx.x >> 6;   // 0..7
    const int ln  = threadIdx.x & 63;
    const int oy  = oyt * 8 + wv;
    const int ox  = oxt * 64 + ln;

    const float unit = unit_p[0];
    const float* imgb = img + (size_t)b * (C_ * H_ * W_);
    const int kbase = b * (K2_ * HWo) + oy * WO_ + ox;   // < 2^25

    // Window origin (orig-image coords), x 4-aligned for float4 staging.
    int wxlo = 128 * oxt - 4;
    wxlo = wxlo < 0 ? 0 : (wxlo > W_ - WX_ ? W_ - WX_ : wxlo);   // 0..888, %4==0
    int wylo = 16 * oyt - 4;
    wylo = wylo < 0 ? 0 : (wylo > H_ - WY_ ? H_ - WY_ : wylo);   // 0..999

    // Phase 1: all 27 stream loads in flight (read-once -> nontemporal).
    float wk[K2_], oh[K2_], ov[K2_];
#pragma unroll
    for (int k = 0; k < K2_; ++k) {
        wk[k] = __builtin_nontemporal_load(kern + kbase + k * HWo);
        oh[k] = __builtin_nontemporal_load(offh + kbase + k * HWo);
        ov[k] = __builtin_nontemporal_load(offv + kbase + k * HWo);
    }

    // Phase 2: stage window into LDS as packed pairs:
    // shp[ch][row][c] = half2(img[row][c], img[row][c+1]).
#pragma unroll
    for (int i = 0; i < 5; ++i) {
        const int it = threadIdx.x + i * TPB_;
        if (it < NF4_) {
            const int ch  = it / (WY_ * WX4_);
            const int rem = it - ch * (WY_ * WX4_);
            const int row = rem / WX4_;
            const int c4  = rem - row * WX4_;
            const float* src = imgb + ch * (H_ * W_) + (wylo + row) * W_ + wxlo;
            const float4 v = ((const float4*)src)[c4];
            int gx = 4 * c4 + 4;                       // next element
            gx = (wxlo + gx > W_ - 1) ? (W_ - 1 - wxlo) : gx;  // clamp (unread pair)
            const float nx = src[gx];
            __half2 p0 = __float22half2_rn(make_float2(v.x, v.y));
            __half2 p1 = __float22half2_rn(make_float2(v.y, v.z));
            __half2 p2 = __float22half2_rn(make_float2(v.z, v.w));
            __half2 p3 = __float22half2_rn(make_float2(v.w, nx));
            __half2* dst = shp + ch * WCH_ + row * WX_ + 4 * c4;
            dst[0] = p0; dst[1] = p1; dst[2] = p2; dst[3] = p3;
        }
    }
    __syncthreads();

    // (ox+0.5)/WO*W - 0.5 == 2*ox + 0.5  (exact in fp32; W/WO = 2)
    const float cx = 2.0f * (float)ox + 0.5f;
    const float cy = 2.0f * (float)oy + 0.5f;

    float acc0 = 0.0f, acc1 = 0.0f, acc2 = 0.0f;

    // Phase 3: taps, fully unrolled; fdot2 LDS fast path + exact fallback.
#pragma unroll
    for (int k = 0; k < K2_; ++k) {
        const float px = cx + (float)(k % KS_) + oh[k] * unit;
        const float py = cy + (float)(k / KS_) + ov[k] * unit;

        const float fx = floorf(px);
        const float fy = floorf(py);
        const float a  = px - fx;   // alpha
        const float bt = py - fy;   // beta

        // raw corner (orig coords); if in window, clip is inactive and
        // reflect is identity (window subset of [0,W-1]x[0,H-1]).
        const int x0 = (int)fx - 1;
        const int y0 = (int)fy - 1;

        const float wt = wk[k] * (1.0f - bt);
        const float wb = wk[k] * bt;

        const bool inwin = (x0 >= wxlo) & (x0 <= wxlo + WX_ - 2)
                         & (y0 >= wylo) & (y0 <= wylo + WY_ - 2);

        if (inwin) {
            const float ax0 = 1.0f - a;
            // fold row weights into packed half2: one fdot2 per row per ch
            const h2v axt = __builtin_amdgcn_cvt_pkrtz(wt * ax0, wt * a);
            const h2v axb = __builtin_amdgcn_cvt_pkrtz(wb * ax0, wb * a);
            const int i_t = (y0 - wylo) * WX_ + (x0 - wxlo);
            {
                const __half2* hp = shp;
                acc0 = __builtin_amdgcn_fdot2(ldh2(hp + i_t),       axt, acc0, false);
                acc0 = __builtin_amdgcn_fdot2(ldh2(hp + i_t + WX_), axb, acc0, false);
            }
            {
                const __half2* hp = shp + WCH_;
                acc1 = __builtin_amdgcn_fdot2(ldh2(hp + i_t),       axt, acc1, false);
                acc1 = __builtin_amdgcn_fdot2(ldh2(hp + i_t + WX_), axb, acc1, false);
            }
            {
                const __half2* hp = shp + 2 * WCH_;
                acc2 = __builtin_amdgcn_fdot2(ldh2(hp + i_t),       axt, acc2, false);
                acc2 = __builtin_amdgcn_fdot2(ldh2(hp + i_t + WX_), axb, acc2, false);
            }
        } else {
            // exact reference semantics: clip in padded coords + reflect,
            // fp32 global reads (precision preserved for outliers).
            int xL = (int)fx; xL = xL < 0 ? 0 : (xL > WP_ - 1 ? WP_ - 1 : xL);
            int xR = xL + 1;  xR = xR > WP_ - 1 ? WP_ - 1 : xR;
            int yT = (int)fy; yT = yT < 0 ? 0 : (yT > HP_ - 1 ? HP_ - 1 : yT);
            int yB = yT + 1;  yB = yB > HP_ - 1 ? HP_ - 1 : yB;

            int xl = xL - 1; xl = (xl < 0) ? -xl : (xl >= W_ ? 2 * W_ - 2 - xl : xl);
            int xr = xR - 1; xr = (xr < 0) ? -xr : (xr >= W_ ? 2 * W_ - 2 - xr : xr);
            int yt = yT - 1; yt = (yt < 0) ? -yt : (yt >= H_ ? 2 * H_ - 2 - yt : yt);
            int yb = yB - 1; yb = (yb < 0) ? -yb : (yb >= H_ ? 2 * H_ - 2 - yb : yb);

            const int base = xl < xr ? xl : xr;
            const float ax0 = ((xl == base) ? (1.0f - a) : 0.0f)
                            + ((xr == base) ? a : 0.0f);
            const float ax1 = 1.0f - ax0;

            const int r0 = yt * W_ + base;
            const int r1 = yb * W_ + base;
            {
                const float2 v = ld2(imgb + r0);
                const float2 u = ld2(imgb + r1);
                acc0 = fmaf(wt, fmaf(ax0, v.x, ax1 * v.y),
                       fmaf(wb, fmaf(ax0, u.x, ax1 * u.y), acc0));
            }
            {
                const float2 v = ld2(imgb + H_ * W_ + r0);
                const float2 u = ld2(imgb + H_ * W_ + r1);
                acc1 = fmaf(wt, fmaf(ax0, v.x, ax1 * v.y),
                       fmaf(wb, fmaf(ax0, u.x, ax1 * u.y), acc1));
            }
            {
                const float2 v = ld2(imgb + 2 * H_ * W_ + r0);
                const float2 u = ld2(imgb + 2 * H_ * W_ + r1);
                acc2 = fmaf(wt, fmaf(ax0, v.x, ax1 * v.y),
                       fmaf(wb, fmaf(ax0, u.x, ax1 * u.y), acc2));
            }
        }
    }

    const int obase = b * (C_ * HWo) + oy * WO_ + ox;
    out[obase]           = acc0;
    out[obase + HWo]     = acc1;
    out[obase + 2 * HWo] = acc2;
}

extern "C" void kernel_launch(void* const* d_in, const int* in_sizes, int n_in,
                              void* d_out, int out_size, void* d_ws, size_t ws_size,
                              hipStream_t stream) {
    const float* img  = (const float*)d_in[0];
    const float* kern = (const float*)d_in[1];
    const float* offh = (const float*)d_in[2];
    const float* offv = (const float*)d_in[3];
    const float* unit = (const float*)d_in[4];
    float* out = (float*)d_out;

    ds_kernel<<<NBLK_, TPB_, 0, stream>>>(img, kern, offh, offv, unit, out);
}